// Round 10
// baseline (699.837 us; speedup 1.0000x reference)
//
#include <hip/hip_runtime.h>
#include <cstddef>

typedef unsigned short u16;
typedef _Float16 f16x8 __attribute__((ext_vector_type(8)));
typedef float f32x4 __attribute__((ext_vector_type(4)));

#define NB  8
#define NW  5
#define NS  5
#define NC  640
#define NHW 100
#define NQ  75
#define ND  500   // S*hw descriptors
#define NDP 512   // padded cols
#define NR  7500  // Q*hw rows
#define NRP 7552  // padded rows = 118*64
#define NRU 118   // 64-row units

// workspace byte offsets
#define OFF_SUP   ((size_t)0)           // u16 [NB][NW][NDP][NC]  26,214,400 B
#define OFF_ABF   ((size_t)26214400)    // u16 [NB][NRP][NC]      77,332,480 B
#define OFF_QRN   ((size_t)103546880)   // f32 [NB][NRP]             241,664 B
#define OFF_PROTO ((size_t)103788544)   // f32 [NB][NW][NC]          102,400 B

__device__ __forceinline__ u16 f2h_bits(float x) {
  _Float16 h = (_Float16)x;
  return __builtin_bit_cast(u16, h);
}
__device__ __forceinline__ float h2f_bits(u16 u) {
  return (float)__builtin_bit_cast(_Float16, u);
}

// async global->LDS DMA, 16B per lane: lane l deposits at lds_base + l*16.
__device__ __forceinline__ void gload_lds16(const u16* g, u16* l) {
  __builtin_amdgcn_global_load_lds(
      (const __attribute__((address_space(1))) unsigned int*)g,
      (__attribute__((address_space(3))) unsigned int*)l,
      16, 0, 0);
}

__device__ __forceinline__ float block_sum(float v, float* sc, int t) {
  v += __shfl_xor(v, 32, 64);
  v += __shfl_xor(v, 16, 64);
  v += __shfl_xor(v, 8, 64);
  v += __shfl_xor(v, 4, 64);
  v += __shfl_xor(v, 2, 64);
  v += __shfl_xor(v, 1, 64);
  __syncthreads();
  if ((t & 63) == 0) sc[t >> 6] = v;
  __syncthreads();
  return sc[0] + sc[1] + sc[2] + sc[3];
}

// sorted-ascending top-5 insert (all indices compile-time -> stays in VGPRs)
__device__ __forceinline__ void t5_insert(float (&t5)[5], float v) {
  if (v > t5[0]) {
    t5[0] = v; float tmp;
    if (t5[0] > t5[1]) { tmp = t5[0]; t5[0] = t5[1]; t5[1] = tmp; }
    if (t5[1] > t5[2]) { tmp = t5[1]; t5[1] = t5[2]; t5[2] = tmp; }
    if (t5[2] > t5[3]) { tmp = t5[2]; t5[2] = t5[3]; t5[3] = tmp; }
    if (t5[3] > t5[4]) { tmp = t5[3]; t5[3] = t5[4]; t5[4] = tmp; }
  }
}

// k1: per (b,w,32-channel group). Single coalesced global pass through an LDS
// fp16 tile; per-channel descriptor-axis norms + raw proto sums from the tile.
__global__ __launch_bounds__(256) void k1_sup(const float* __restrict__ xs,
                                              u16* __restrict__ sup2,
                                              float* __restrict__ proto_g) {
  const int cc = blockIdx.x, w = blockIdx.y, b = blockIdx.z;
  const int t = threadIdx.x;
  __shared__ u16 tile[512 * 34];   // [d][c], stride 34 (17 words, odd -> spread)
  __shared__ float rn[32];
  const size_t bw = (size_t)b * NW + w;
  const float* xbase = xs + bw * NS * NC * NHW;   // [S][C][hw]
  const int cb = cc * 32;

  for (int s = 0; s < NS; s++) {
    const float4* rb = (const float4*)(xbase + ((size_t)s * NC + cb) * NHW);
    for (int i4 = t; i4 < 800; i4 += 256) {       // fully coalesced float4
      const float4 v = rb[i4];
      const int c = i4 / 25, p4 = i4 % 25;
      const int d = s * NHW + p4 * 4;
      tile[(d    ) * 34 + c] = f2h_bits(v.x);
      tile[(d + 1) * 34 + c] = f2h_bits(v.y);
      tile[(d + 2) * 34 + c] = f2h_bits(v.z);
      tile[(d + 3) * 34 + c] = f2h_bits(v.w);
    }
  }
  if (t < 384) tile[(500 + (t >> 5)) * 34 + (t & 31)] = 0;  // zero pad d 500..511
  __syncthreads();
  {
    const int c = t >> 3, part = t & 7;   // 32 c x 8 partials, from LDS
    float ss = 0.f, sm = 0.f;
    for (int d = part; d < ND; d += 8) {
      const float x = h2f_bits(tile[d * 34 + c]);
      ss += x * x; sm += x;
    }
    ss += __shfl_xor(ss, 1, 64); ss += __shfl_xor(ss, 2, 64); ss += __shfl_xor(ss, 4, 64);
    sm += __shfl_xor(sm, 1, 64); sm += __shfl_xor(sm, 2, 64); sm += __shfl_xor(sm, 4, 64);
    if (part == 0) {
      rn[c] = 1.0f / sqrtf(ss);
      proto_g[bw * NC + cb + c] = sm;     // raw sum; mean scales cancel in cosine
    }
  }
  __syncthreads();
  u16* obase = sup2 + bw * NDP * NC + cb;
  for (int idx = t; idx < 512 * 32; idx += 256) {
    const int cl = idx & 31, d = idx >> 5;
    obase[(size_t)d * NC + cl] = f2h_bits(h2f_bits(tile[d * 34 + cl]) * rn[cl]);
  }
}

// k2: per (b,q): coalesced transpose x_query -> Abf fp16 (unnormalized),
// qm/qs via explicit LDS reductions (no atomics), cosine branch -> out.
__global__ __launch_bounds__(256) void k2_query(const float* __restrict__ xq,
                                                const float* __restrict__ proto_g,
                                                const float* __restrict__ rcosp,
                                                u16* __restrict__ Abf,
                                                float* __restrict__ qrn,
                                                float* __restrict__ out) {
  const int q = blockIdx.x, b = blockIdx.y;
  const int t = threadIdx.x;
  __shared__ u16 tile[128 * 106];   // [c_local][p], stride 106 (53 words, odd)
  __shared__ float qm[NC];
  __shared__ float qs[NHW];
  __shared__ float sc[4];
  const float* xbase = xq + ((size_t)b * NQ + q) * NC * NHW;
  u16* abase = Abf + ((size_t)b * NRP + (size_t)q * NHW) * NC;

  if (t < NHW) qs[t] = 0.f;
  __syncthreads();

  for (int cc = 0; cc < 5; cc++) {          // 128-channel chunks
    const float4* rb = (const float4*)(xbase + (size_t)cc * 128 * NHW);
    for (int i4 = t; i4 < 3200; i4 += 256) {  // coalesced float4 reads
      const float4 xv = rb[i4];
      const int e = i4 * 4;
      const int p = e % NHW, cl = e / NHW;    // 4|100: never crosses a channel
      const unsigned lo = (unsigned)f2h_bits(xv.x) | ((unsigned)f2h_bits(xv.y) << 16);
      const unsigned hi = (unsigned)f2h_bits(xv.z) | ((unsigned)f2h_bits(xv.w) << 16);
      unsigned* tw = (unsigned*)&tile[cl * 106 + p];  // 8B-aligned (212*cl + 8*p4)
      tw[0] = lo; tw[1] = hi;
    }
    __syncthreads();
    if (t < 128) {                // qm: per-channel sum over p (dword reads)
      float s = 0.f;
      const unsigned* row = (const unsigned*)&tile[t * 106];
      for (int j = 0; j < 50; j++) {
        const unsigned u = row[j];
        s += h2f_bits((u16)(u & 0xffffu)) + h2f_bits((u16)(u >> 16));
      }
      qm[cc * 128 + t] = s;
    } else if (t < 228) {         // qs: per-p sumsq over this chunk's 128 c
      const int p = t - 128;
      float s = 0.f;
      for (int c = 0; c < 128; c++) {
        const float x = h2f_bits(tile[c * 106 + p]);
        s += x * x;
      }
      qs[p] += s;
    }
    {
      const int c0 = t & 63, pr = t >> 6;
      for (int p = pr; p < NHW; p += 4) {   // coalesced 128B fp16 writes
        abase[(size_t)p * NC + cc * 128 + c0]      = tile[c0 * 106 + p];
        abase[(size_t)p * NC + cc * 128 + c0 + 64] = tile[(c0 + 64) * 106 + p];
      }
    }
    __syncthreads();
  }
  if (t < NHW) qrn[(size_t)b * NRP + q * NHW + t] = 1.0f / sqrtf(qs[t]);

  // cosine: qn.pn = (qm.proto)/(|qm||proto|)
  float part = 0.f;
  for (int c = t; c < NC; c += 256) part += qm[c] * qm[c];
  const float qq = block_sum(part, sc, t);
  const float rcos = rcosp[0];
  for (int w = 0; w < NW; w++) {
    const float* pr_ = proto_g + ((size_t)b * NW + w) * NC;
    float dp = 0.f, pp = 0.f;
    for (int c = t; c < NC; c += 256) { const float pv = pr_[c]; dp += qm[c] * pv; pp += pv * pv; }
    dp = block_sum(dp, sc, t);
    pp = block_sum(pp, sc, t);
    if (t == 0) out[((size_t)b * NQ + q) * NW + w] = rcos * dp / sqrtf(qq * pp);
  }
  if (q == 0) {   // zero A pad rows [7500,7552) for this b
    u16* pz = Abf + ((size_t)b * NRP + NR) * NC;
    for (int i = t; i < (NRP - NR) * NC; i += 256) pz[i] = 0;
  }
}

// k4: BARRIER-FREE single-wave blocks. One 64-thread wave owns a 64-row x
// 512-desc unit; ct loop (4 x 128 desc) keeps all descriptors in-block so
// per-row top-5 is complete. Per BK=32 slab: 12 global_load_lds DMA ops
// (4 A-groups + 8 B-groups, fragment-linear: group g slot l = (row g*16 +
// (l&15), k-chunk l>>4)), double-buffered 24KB private LDS, counted
// s_waitcnt vmcnt(12) only -- ZERO s_barrier / __syncthreads in the whole
// kernel, so no cross-wave coupling (the R1..R9 bottleneck: all pipes <30%
// while 80 barrier-phases serialize). 12 lane-linear conflict-free
// ds_read_b128 + 32 MFMA per phase; acc[8][4] (128 f32, R4-proven budget).
// XCD swizzle: 4720 = 8 x 590; b = id&7 (one episode per XCD: B slice
// 3.2MB L2-resident), ru outer / w inner (A-unit L2-hot across 5 w).
__global__ __launch_bounds__(64, 2) void k4_dn4(const u16* __restrict__ Abf,
                                                const u16* __restrict__ sup2,
                                                const float* __restrict__ qrn,
                                                const float* __restrict__ rdn4p,
                                                const int* __restrict__ nkp,
                                                float* __restrict__ out) {
  const int id = blockIdx.x;
  const int b = id & 7;           // one episode per XCD
  const int k = id >> 3;          // 0..589 within XCD
  const int ru = k / 5;           // row unit outer: A-tile hot across w
  const int w = k % 5;

  const int lane = threadIdx.x & 63;
  const int m = lane & 15, quad = lane >> 4;

  // [buf][group*512 + lane*8]: groups 0..3 = A rows (16 each), 4..11 = B desc
  __shared__ __align__(16) u16 stg[2][6144];   // 24,576 B

  const u16* Ab = Abf + ((size_t)b * NRP + (size_t)ru * 64) * NC;
  const u16* Bb = sup2 + (((size_t)b * NW + w) * NDP) * NC;

  const size_t lrow = (size_t)m * NC + (size_t)quad * 8;  // per-lane row/k offset
  const int l8 = lane * 8;

// 12 DMA ops staging slab (CT_ desc-chunk, K0_) into buffer BUF_
#define ISSUE(BUF_, CT_, K0_) do {                                        \
    u16* s_ = &stg[BUF_][0];                                              \
    const u16* a_ = Ab + lrow + (K0_);                                    \
    gload_lds16(a_,                   s_ + l8);                           \
    gload_lds16(a_ + (size_t)16 * NC, s_ + 512 + l8);                     \
    gload_lds16(a_ + (size_t)32 * NC, s_ + 1024 + l8);                    \
    gload_lds16(a_ + (size_t)48 * NC, s_ + 1536 + l8);                    \
    const u16* b_ = Bb + (size_t)(CT_) * (128 * NC) + lrow + (K0_);       \
    gload_lds16(b_,                    s_ + 2048 + l8);                   \
    gload_lds16(b_ + (size_t)16 * NC,  s_ + 2560 + l8);                   \
    gload_lds16(b_ + (size_t)32 * NC,  s_ + 3072 + l8);                   \
    gload_lds16(b_ + (size_t)48 * NC,  s_ + 3584 + l8);                   \
    gload_lds16(b_ + (size_t)64 * NC,  s_ + 4096 + l8);                   \
    gload_lds16(b_ + (size_t)80 * NC,  s_ + 4608 + l8);                   \
    gload_lds16(b_ + (size_t)96 * NC,  s_ + 5120 + l8);                   \
    gload_lds16(b_ + (size_t)112 * NC, s_ + 5632 + l8);                   \
  } while (0)

  float t5[4][5];   // per-lane top-5 (sorted ascending) for 4 query rows
#pragma unroll
  for (int qt = 0; qt < 4; qt++)
#pragma unroll
    for (int i = 0; i < 5; i++) t5[qt][i] = -3e38f;

  // prologue: slab0 -> buf0, slab1 -> buf1 (both in flight)
  ISSUE(0, 0, 0);
  ISSUE(1, 0, 32);

  for (int ct = 0; ct < 4; ct++) {
    f32x4 acc[8][4];   // [dt descriptor-tile][qt query-row-tile]
#pragma unroll
    for (int dt = 0; dt < 8; dt++)
#pragma unroll
      for (int qt = 0; qt < 4; qt++)
        acc[dt][qt] = (f32x4){0.f, 0.f, 0.f, 0.f};

    for (int ks = 0; ks < 20; ks++) {
      // slab g = ct*20+ks in buf[ks&1]: wait its 12 DMAs (12 = next slab's
      // ops stay in flight; never drain to 0 except the very last phase)
      if (ct == 3 && ks == 19) {
        asm volatile("s_waitcnt vmcnt(0)" ::: "memory");
      } else {
        asm volatile("s_waitcnt vmcnt(12)" ::: "memory");
      }
      __builtin_amdgcn_sched_barrier(0);
      const u16* la = &stg[ks & 1][0];
      f16x8 af0, af1, af2, af3, bf0, bf1, bf2, bf3, bf4, bf5, bf6, bf7;
      af0 = *(const f16x8*)&la[l8];
      af1 = *(const f16x8*)&la[512 + l8];
      af2 = *(const f16x8*)&la[1024 + l8];
      af3 = *(const f16x8*)&la[1536 + l8];
      bf0 = *(const f16x8*)&la[2048 + l8];
      bf1 = *(const f16x8*)&la[2560 + l8];
      bf2 = *(const f16x8*)&la[3072 + l8];
      bf3 = *(const f16x8*)&la[3584 + l8];
      bf4 = *(const f16x8*)&la[4096 + l8];
      bf5 = *(const f16x8*)&la[4608 + l8];
      bf6 = *(const f16x8*)&la[5120 + l8];
      bf7 = *(const f16x8*)&la[5632 + l8];
      // swapped operands: D[desc = quad*4+reg (+dt*16+ct*128)][row m]
      acc[0][0] = __builtin_amdgcn_mfma_f32_16x16x32_f16(bf0, af0, acc[0][0], 0, 0, 0);
      acc[0][1] = __builtin_amdgcn_mfma_f32_16x16x32_f16(bf0, af1, acc[0][1], 0, 0, 0);
      acc[0][2] = __builtin_amdgcn_mfma_f32_16x16x32_f16(bf0, af2, acc[0][2], 0, 0, 0);
      acc[0][3] = __builtin_amdgcn_mfma_f32_16x16x32_f16(bf0, af3, acc[0][3], 0, 0, 0);
      acc[1][0] = __builtin_amdgcn_mfma_f32_16x16x32_f16(bf1, af0, acc[1][0], 0, 0, 0);
      acc[1][1] = __builtin_amdgcn_mfma_f32_16x16x32_f16(bf1, af1, acc[1][1], 0, 0, 0);
      acc[1][2] = __builtin_amdgcn_mfma_f32_16x16x32_f16(bf1, af2, acc[1][2], 0, 0, 0);
      acc[1][3] = __builtin_amdgcn_mfma_f32_16x16x32_f16(bf1, af3, acc[1][3], 0, 0, 0);
      acc[2][0] = __builtin_amdgcn_mfma_f32_16x16x32_f16(bf2, af0, acc[2][0], 0, 0, 0);
      acc[2][1] = __builtin_amdgcn_mfma_f32_16x16x32_f16(bf2, af1, acc[2][1], 0, 0, 0);
      acc[2][2] = __builtin_amdgcn_mfma_f32_16x16x32_f16(bf2, af2, acc[2][2], 0, 0, 0);
      acc[2][3] = __builtin_amdgcn_mfma_f32_16x16x32_f16(bf2, af3, acc[2][3], 0, 0, 0);
      acc[3][0] = __builtin_amdgcn_mfma_f32_16x16x32_f16(bf3, af0, acc[3][0], 0, 0, 0);
      acc[3][1] = __builtin_amdgcn_mfma_f32_16x16x32_f16(bf3, af1, acc[3][1], 0, 0, 0);
      acc[3][2] = __builtin_amdgcn_mfma_f32_16x16x32_f16(bf3, af2, acc[3][2], 0, 0, 0);
      acc[3][3] = __builtin_amdgcn_mfma_f32_16x16x32_f16(bf3, af3, acc[3][3], 0, 0, 0);
      acc[4][0] = __builtin_amdgcn_mfma_f32_16x16x32_f16(bf4, af0, acc[4][0], 0, 0, 0);
      acc[4][1] = __builtin_amdgcn_mfma_f32_16x16x32_f16(bf4, af1, acc[4][1], 0, 0, 0);
      acc[4][2] = __builtin_amdgcn_mfma_f32_16x16x32_f16(bf4, af2, acc[4][2], 0, 0, 0);
      acc[4][3] = __builtin_amdgcn_mfma_f32_16x16x32_f16(bf4, af3, acc[4][3], 0, 0, 0);
      acc[5][0] = __builtin_amdgcn_mfma_f32_16x16x32_f16(bf5, af0, acc[5][0], 0, 0, 0);
      acc[5][1] = __builtin_amdgcn_mfma_f32_16x16x32_f16(bf5, af1, acc[5][1], 0, 0, 0);
      acc[5][2] = __builtin_amdgcn_mfma_f32_16x16x32_f16(bf5, af2, acc[5][2], 0, 0, 0);
      acc[5][3] = __builtin_amdgcn_mfma_f32_16x16x32_f16(bf5, af3, acc[5][3], 0, 0, 0);
      acc[6][0] = __builtin_amdgcn_mfma_f32_16x16x32_f16(bf6, af0, acc[6][0], 0, 0, 0);
      acc[6][1] = __builtin_amdgcn_mfma_f32_16x16x32_f16(bf6, af1, acc[6][1], 0, 0, 0);
      acc[6][2] = __builtin_amdgcn_mfma_f32_16x16x32_f16(bf6, af2, acc[6][2], 0, 0, 0);
      acc[6][3] = __builtin_amdgcn_mfma_f32_16x16x32_f16(bf6, af3, acc[6][3], 0, 0, 0);
      acc[7][0] = __builtin_amdgcn_mfma_f32_16x16x32_f16(bf7, af0, acc[7][0], 0, 0, 0);
      acc[7][1] = __builtin_amdgcn_mfma_f32_16x16x32_f16(bf7, af1, acc[7][1], 0, 0, 0);
      acc[7][2] = __builtin_amdgcn_mfma_f32_16x16x32_f16(bf7, af2, acc[7][2], 0, 0, 0);
      acc[7][3] = __builtin_amdgcn_mfma_f32_16x16x32_f16(bf7, af3, acc[7][3], 0, 0, 0);
      // ds_reads retired (MFMAs consumed them); now safe to overwrite buf
      asm volatile("s_waitcnt lgkmcnt(0)" ::: "memory");
      __builtin_amdgcn_sched_barrier(0);
      if (!(ct == 3 && ks >= 18)) {
        const int ctn = (ks < 18) ? ct : ct + 1;
        const int k0n = ((ks < 18) ? (ks + 2) : (ks - 18)) * 32;
        ISSUE(ks & 1, ctn, k0n);
      }
    }

    // top-5 scan from registers; d = ct*128 + dt*16 + quad*4 + r.
    // only (ct==3, dt==7) touches pad desc 500..511: valid iff quad==0.
#pragma unroll
    for (int dt = 0; dt < 8; dt++) {
      const bool tail = (ct == 3 && dt == 7);
#pragma unroll
      for (int qt = 0; qt < 4; qt++)
#pragma unroll
        for (int r = 0; r < 4; r++)
          if (!tail || quad == 0) t5_insert(t5[qt], acc[dt][qt][r]);
    }
  }
#undef ISSUE

  // merge across the 4 quads (disjoint descriptor subsets, same query rows)
#pragma unroll
  for (int qt = 0; qt < 4; qt++) {
    float rec[5];
#pragma unroll
    for (int i = 0; i < 5; i++) rec[i] = __shfl_xor(t5[qt][i], 16, 64);
#pragma unroll
    for (int i = 0; i < 5; i++) t5_insert(t5[qt], rec[i]);
#pragma unroll
    for (int i = 0; i < 5; i++) rec[i] = __shfl_xor(t5[qt][i], 32, 64);
#pragma unroll
    for (int i = 0; i < 5; i++) t5_insert(t5[qt], rec[i]);
  }

  if (quad == 0) {
    const float scale = rdn4p[0] / (float)nkp[0];
    const float* qrb = qrn + (size_t)b * NRP;
#pragma unroll
    for (int qt = 0; qt < 4; qt++) {
      const int r = ru * 64 + qt * 16 + m;
      if (r < NR) {
        const float s = t5[qt][0] + t5[qt][1] + t5[qt][2] + t5[qt][3] + t5[qt][4];
        // fold per-row 1/|qd| (positive scale commutes with top-k), r_dn4, 1/k
        const float contrib = s * qrb[r] * scale;
        const int qi = r / NHW;
        atomicAdd(&out[((size_t)b * NQ + qi) * NW + w], contrib);
      }
    }
  }
}

extern "C" void kernel_launch(void* const* d_in, const int* in_sizes, int n_in,
                              void* d_out, int out_size, void* d_ws, size_t ws_size,
                              hipStream_t stream) {
  (void)in_sizes; (void)n_in; (void)out_size; (void)ws_size;
  const float* xs   = (const float*)d_in[0];
  const float* xq   = (const float*)d_in[1];
  const float* rcos = (const float*)d_in[2];
  const float* rdn4 = (const float*)d_in[3];
  const int*   nk   = (const int*)d_in[4];
  float* out = (float*)d_out;
  char* ws = (char*)d_ws;
  u16*   sup2  = (u16*)(ws + OFF_SUP);
  u16*   Abf   = (u16*)(ws + OFF_ABF);
  float* qrn   = (float*)(ws + OFF_QRN);
  float* proto = (float*)(ws + OFF_PROTO);

  k1_sup <<<dim3(20, NW, NB),  dim3(256), 0, stream>>>(xs, sup2, proto);
  k2_query<<<dim3(NQ, NB),     dim3(256), 0, stream>>>(xq, proto, rcos, Abf, qrn, out);
  k4_dn4 <<<dim3(NRU * NW * NB), dim3(64), 0, stream>>>(Abf, sup2, qrn, rdn4, nk, out);
}